// Round 5
// baseline (174.213 us; speedup 1.0000x reference)
//
#include <hip/hip_runtime.h>
#include <math.h>

#define B_ 8
#define T_ 2048
#define D_ 1024
#define HS_ 64

typedef _Float16 f16x8 __attribute__((ext_vector_type(8)));
typedef float f32x4 __attribute__((ext_vector_type(4)));

// ---------------------------------------------------------------------------
// ws layout (f16 elements unless noted):
//   qf : [B*T][64]      @ 0          (1,048,576)
//   kf : [B*T][64]      @ 1,048,576
//   vT : [B][64][T]     @ 2,097,152
//   Wt : [192][1024]    @ 3,145,728  (196,608)  rows: Wq^T|Wk^T|Wv^T
//   Op : [640][64][64]  @ 3,342,336  (2,621,440) unnormalized O partials
//   ml : [640][128] f32 @ byte 11,927,552 (m[64] then l[64] per slot)
// ---------------------------------------------------------------------------

// Stage 0: transpose Wq|Wk|Wv (fp32 [1024][64]) -> Wt f16 [192][1024]
__global__ __launch_bounds__(256) void wt_kernel(
    const float* __restrict__ Wq, const float* __restrict__ Wk,
    const float* __restrict__ Wv, _Float16* __restrict__ Wt)
{
    __shared__ _Float16 Tt[64][72];
    const float* W = (blockIdx.y == 0) ? Wq : (blockIdx.y == 1) ? Wk : Wv;
    const int t  = threadIdx.x;
    const int k0 = blockIdx.x * 64;
    {
        const int r = t >> 2, c0 = (t & 3) * 16;
#pragma unroll
        for (int i = 0; i < 4; ++i) {
            float4 w = *(const float4*)&W[(size_t)(k0 + r) * HS_ + c0 + i * 4];
            Tt[c0 + i * 4 + 0][r] = (_Float16)w.x;
            Tt[c0 + i * 4 + 1][r] = (_Float16)w.y;
            Tt[c0 + i * 4 + 2][r] = (_Float16)w.z;
            Tt[c0 + i * 4 + 3][r] = (_Float16)w.w;
        }
    }
    __syncthreads();
    {
        const int n = t >> 2, ko = (t & 3) * 16;
        const size_t dst = (size_t)(blockIdx.y * 64 + n) * D_ + k0 + ko;
        *(int4*)&Wt[dst]     = *(int4*)&Tt[n][ko];
        *(int4*)&Wt[dst + 8] = *(int4*)&Tt[n][ko + 8];
    }
}

// ---------------------------------------------------------------------------
// Stage 1: QKV projection, f16 MFMA.  Grid 512, block 512 = 8 waves.
// M-tile 32.  wave = (kw<<1)|w2 : w2 = row group (16 rows), kw = K-quarter
// (256 deep, 8 steps of 32).  4 waves/SIMD when 2 blocks/CU co-resident ->
// latency hidden by TLP.  Epilogue: 4-stage f32 reduce in LDS, pack f16,
// coalesced writes.
// ---------------------------------------------------------------------------
__global__ __launch_bounds__(512, 4) void qkv_kernel(
    const float* __restrict__ x, const _Float16* __restrict__ Wt,
    _Float16* __restrict__ qf, _Float16* __restrict__ kf,
    _Float16* __restrict__ vT)
{
    __shared__ float    CsF[32][200];   // f32 cross-K partial buffer (25.6 KB)
    __shared__ _Float16 CsH[32][200];   // packed f16 result (12.8 KB)

    const int t    = threadIdx.x;
    const int m0   = blockIdx.x * 32;
    const int lane = t & 63, wave = t >> 6;
    const int w2   = wave & 1;           // row group (16 rows)
    const int kw   = wave >> 1;          // K-quarter
    const int lid  = lane & 15, quad = lane >> 4;

    const float*    xp = x  + (size_t)(m0 + w2 * 16 + lid) * D_ + kw * 256 + quad * 8;
    const _Float16* wp = Wt + (size_t)lid * D_ + kw * 256 + quad * 8;

    f32x4 acc[12];
#pragma unroll
    for (int i = 0; i < 12; ++i) acc[i] = f32x4{0.f, 0.f, 0.f, 0.f};

    // prologue: load step 0
    float4 xc0 = *(const float4*)(xp);
    float4 xc1 = *(const float4*)(xp + 4);
    f16x8 bc[12];
#pragma unroll
    for (int nt = 0; nt < 12; ++nt)
        bc[nt] = *(const f16x8*)(wp + (size_t)nt * 16 * D_);

    // 8 steps of k=32 over this wave's 256-deep K quarter
#pragma unroll
    for (int s = 0; s < 8; ++s) {
        float4 xn0, xn1;
        f16x8 bn[12];
        if (s < 7) {
            const int ko = (s + 1) * 32;
            xn0 = *(const float4*)(xp + ko);
            xn1 = *(const float4*)(xp + ko + 4);
#pragma unroll
            for (int nt = 0; nt < 12; ++nt)
                bn[nt] = *(const f16x8*)(wp + (size_t)nt * 16 * D_ + ko);
        }
        const f16x8 a = {(_Float16)xc0.x, (_Float16)xc0.y, (_Float16)xc0.z, (_Float16)xc0.w,
                         (_Float16)xc1.x, (_Float16)xc1.y, (_Float16)xc1.z, (_Float16)xc1.w};
#pragma unroll
        for (int nt = 0; nt < 12; ++nt)
            acc[nt] = __builtin_amdgcn_mfma_f32_16x16x32_f16(a, bc[nt], acc[nt], 0, 0, 0);
        if (s < 7) {
            xc0 = xn0; xc1 = xn1;
#pragma unroll
            for (int nt = 0; nt < 12; ++nt) bc[nt] = bn[nt];
        }
    }

    // ---- epilogue: staged reduce over 4 K-quarters ----
    const int rr = w2 * 16 + quad * 4;
    if (kw == 3) {
#pragma unroll
        for (int nt = 0; nt < 12; ++nt)
#pragma unroll
            for (int r = 0; r < 4; ++r)
                CsF[rr + r][nt * 16 + lid] = acc[nt][r];
    }
    __syncthreads();
    if (kw == 2) {
#pragma unroll
        for (int nt = 0; nt < 12; ++nt)
#pragma unroll
            for (int r = 0; r < 4; ++r)
                CsF[rr + r][nt * 16 + lid] += acc[nt][r];
    }
    __syncthreads();
    if (kw == 1) {
#pragma unroll
        for (int nt = 0; nt < 12; ++nt)
#pragma unroll
            for (int r = 0; r < 4; ++r)
                CsF[rr + r][nt * 16 + lid] += acc[nt][r];
    }
    __syncthreads();
    if (kw == 0) {
#pragma unroll
        for (int nt = 0; nt < 12; ++nt)
#pragma unroll
            for (int r = 0; r < 4; ++r)
                CsH[rr + r][nt * 16 + lid] =
                    (_Float16)(acc[nt][r] + CsF[rr + r][nt * 16 + lid]);
    }
    __syncthreads();

    // coalesced writes: t<256 -> q,k rows; t>=256 -> vT transpose-gather
    if (t < 256) {
        const int row = t >> 3;          // 0..31
        const int c8  = (t & 7) * 8;     // 0..56
        const size_t orow = (size_t)(m0 + row) * HS_;
        *(int4*)&qf[orow + c8] = *(int4*)&CsH[row][c8];
        *(int4*)&kf[orow + c8] = *(int4*)&CsH[row][64 + c8];
    } else {
        const int u  = t - 256;
        const int h  = u >> 2;           // 0..63
        const int mo = (u & 3) * 8;      // 0..24
        _Float16 tmp[8];
#pragma unroll
        for (int j = 0; j < 8; ++j) tmp[j] = CsH[mo + j][128 + h];
        const int bi = m0 >> 11, m0loc = m0 & 2047;
        *(int4*)&vT[(size_t)(bi * 64 + h) * T_ + m0loc + mo] = *(int4*)&tmp[0];
    }
}

// ---------------------------------------------------------------------------
// Stage 2: causal flash attention, split-K (chunks of 8 k-tiles = 512 keys).
// (unchanged from Round 3/4)
// ---------------------------------------------------------------------------
__global__ __launch_bounds__(256) void attn_kernel(
    const _Float16* __restrict__ qf, const _Float16* __restrict__ kf,
    const _Float16* __restrict__ vT, _Float16* __restrict__ Opart,
    float* __restrict__ ml, float* __restrict__ out)
{
    __shared__ _Float16 Qs[64][72];
    __shared__ _Float16 Ks[64][72];
    __shared__ _Float16 Vts[64][72];
    __shared__ _Float16 Ps[64][72];

    const int p = blockIdx.x, b = blockIdx.y;
    int qi, c;
    if (p < 8)       { qi = p;                  c = 0; }
    else if (p < 24) { qi = 8  + ((p - 8) >> 1);  c = (p - 8) & 1; }
    else if (p < 48) { qi = 16 + (p - 24) / 3;    c = (p - 24) % 3; }
    else             { qi = 24 + ((p - 48) >> 2); c = (p - 48) & 3; }
    const int kts = c * 8;
    const int kte = min(qi + 1, kts + 8);

    const int q0 = qi * 64;
    const size_t bT = (size_t)b * T_;
    const int t = threadIdx.x;
    const int lane = t & 63, wave = t >> 6;
    const int lid  = lane & 15, quad = lane >> 4;
    const int sr = t >> 2, so = (t & 3) * 16;

    {
        const size_t src = (bT + q0 + sr) * HS_ + so;
        *(int4*)&Qs[sr][so]     = *(const int4*)&qf[src];
        *(int4*)&Qs[sr][so + 8] = *(const int4*)&qf[src + 8];
    }
    __syncthreads();
    const f16x8 aq0 = *(const f16x8*)&Qs[wave * 16 + lid][quad * 8];
    const f16x8 aq1 = *(const f16x8*)&Qs[wave * 16 + lid][32 + quad * 8];

    f32x4 o[4];
#pragma unroll
    for (int i = 0; i < 4; ++i) o[i] = f32x4{0.f, 0.f, 0.f, 0.f};
    float mp[4] = {-1e30f, -1e30f, -1e30f, -1e30f};
    float lr[4] = {0.f, 0.f, 0.f, 0.f};

    const float SC = 0.125f * 1.44269504088896f;   // HS^-0.5 * log2(e)

    int4 kr0, kr1, vr0, vr1;
    {
        const int k0 = kts * 64;
        const size_t ksrc = (bT + k0 + sr) * HS_ + so;
        kr0 = *(const int4*)&kf[ksrc]; kr1 = *(const int4*)&kf[ksrc + 8];
        const size_t vsrc = (size_t)(b * 64 + sr) * T_ + k0 + so;
        vr0 = *(const int4*)&vT[vsrc]; vr1 = *(const int4*)&vT[vsrc + 8];
    }

    for (int kt = kts; kt < kte; ++kt) {
        __syncthreads();
        *(int4*)&Ks[sr][so]      = kr0;
        *(int4*)&Ks[sr][so + 8]  = kr1;
        *(int4*)&Vts[sr][so]     = vr0;
        *(int4*)&Vts[sr][so + 8] = vr1;
        __syncthreads();
        if (kt + 1 < kte) {
            const int k0n = (kt + 1) * 64;
            const size_t ksrc = (bT + k0n + sr) * HS_ + so;
            kr0 = *(const int4*)&kf[ksrc]; kr1 = *(const int4*)&kf[ksrc + 8];
            const size_t vsrc = (size_t)(b * 64 + sr) * T_ + k0n + so;
            vr0 = *(const int4*)&vT[vsrc]; vr1 = *(const int4*)&vT[vsrc + 8];
        }

        f32x4 s[4];
#pragma unroll
        for (int i = 0; i < 4; ++i) s[i] = f32x4{0.f, 0.f, 0.f, 0.f};
#pragma unroll
        for (int nt = 0; nt < 4; ++nt) {
            f16x8 b0 = *(const f16x8*)&Ks[nt * 16 + lid][quad * 8];
            f16x8 b1 = *(const f16x8*)&Ks[nt * 16 + lid][32 + quad * 8];
            s[nt] = __builtin_amdgcn_mfma_f32_16x16x32_f16(aq0, b0, s[nt], 0, 0, 0);
            s[nt] = __builtin_amdgcn_mfma_f32_16x16x32_f16(aq1, b1, s[nt], 0, 0, 0);
        }

        float sv[4][4];
        const bool diag = (kt == qi);
#pragma unroll
        for (int nt = 0; nt < 4; ++nt)
#pragma unroll
            for (int r = 0; r < 4; ++r) {
                float v = s[nt][r] * SC;
                if (diag && (nt * 16 + lid > wave * 16 + quad * 4 + r)) v = -1e30f;
                sv[nt][r] = v;
            }

        float pm[4], al[4], rs[4];
#pragma unroll
        for (int r = 0; r < 4; ++r)
            pm[r] = fmaxf(fmaxf(sv[0][r], sv[1][r]), fmaxf(sv[2][r], sv[3][r]));
#pragma unroll
        for (int d = 1; d < 16; d <<= 1)
#pragma unroll
            for (int r = 0; r < 4; ++r)
                pm[r] = fmaxf(pm[r], __shfl_xor(pm[r], d, 64));
#pragma unroll
        for (int r = 0; r < 4; ++r) {
            const float mn = fmaxf(mp[r], pm[r]);
            al[r] = exp2f(mp[r] - mn);
            mp[r] = mn;
            rs[r] = 0.f;
        }
#pragma unroll
        for (int nt = 0; nt < 4; ++nt)
#pragma unroll
            for (int r = 0; r < 4; ++r) {
                const float pv = exp2f(sv[nt][r] - mp[r]);
                sv[nt][r] = pv;
                rs[r] += pv;
            }
#pragma unroll
        for (int d = 1; d < 16; d <<= 1)
#pragma unroll
            for (int r = 0; r < 4; ++r)
                rs[r] += __shfl_xor(rs[r], d, 64);
#pragma unroll
        for (int r = 0; r < 4; ++r)
            lr[r] = lr[r] * al[r] + rs[r];
#pragma unroll
        for (int nt = 0; nt < 4; ++nt)
#pragma unroll
            for (int r = 0; r < 4; ++r)
                o[nt][r] *= al[r];

#pragma unroll
        for (int nt = 0; nt < 4; ++nt)
#pragma unroll
            for (int r = 0; r < 4; ++r)
                Ps[wave * 16 + quad * 4 + r][nt * 16 + lid] = (_Float16)sv[nt][r];

        const f16x8 ap0 = *(const f16x8*)&Ps[wave * 16 + lid][quad * 8];
        const f16x8 ap1 = *(const f16x8*)&Ps[wave * 16 + lid][32 + quad * 8];
#pragma unroll
        for (int nt = 0; nt < 4; ++nt) {
            f16x8 b0 = *(const f16x8*)&Vts[nt * 16 + lid][quad * 8];
            f16x8 b1 = *(const f16x8*)&Vts[nt * 16 + lid][32 + quad * 8];
            o[nt] = __builtin_amdgcn_mfma_f32_16x16x32_f16(ap0, b0, o[nt], 0, 0, 0);
            o[nt] = __builtin_amdgcn_mfma_f32_16x16x32_f16(ap1, b1, o[nt], 0, 0, 0);
        }
    }

    const int nc = (qi >> 3) + 1;
    if (nc == 1) {
        float inv[4];
#pragma unroll
        for (int r = 0; r < 4; ++r) inv[r] = 1.0f / lr[r];
#pragma unroll
        for (int nt = 0; nt < 4; ++nt)
#pragma unroll
            for (int r = 0; r < 4; ++r)
                out[(bT + q0 + wave * 16 + quad * 4 + r) * HS_ + nt * 16 + lid] =
                    o[nt][r] * inv[r];
    } else {
        const int slot = b * 80 + p;
        _Float16* Ob = Opart + (size_t)slot * 4096;
#pragma unroll
        for (int nt = 0; nt < 4; ++nt)
#pragma unroll
            for (int r = 0; r < 4; ++r)
                Ob[(wave * 16 + quad * 4 + r) * 64 + nt * 16 + lid] = (_Float16)o[nt][r];
        if (lid == 0) {
#pragma unroll
            for (int r = 0; r < 4; ++r) {
                const int row = wave * 16 + quad * 4 + r;
                ml[(size_t)slot * 128 + row]      = mp[r];
                ml[(size_t)slot * 128 + 64 + row] = lr[r];
            }
        }
    }
}

// ---------------------------------------------------------------------------
// Stage 3: combine partials for q-tiles with >=2 chunks (qi >= 8).
// (unchanged)
// ---------------------------------------------------------------------------
__global__ __launch_bounds__(256) void combine_kernel(
    const _Float16* __restrict__ Opart, const float* __restrict__ ml,
    float* __restrict__ out)
{
    const int qi = 8 + blockIdx.x, b = blockIdx.y;
    const int g = qi >> 3, nc = g + 1;
    const int poff = 8 * (g * (g + 1) / 2) + (qi & 7) * nc;
    const int t = threadIdx.x, row = t >> 2, c0 = (t & 3) * 16;

    float mv[4], M = -1e30f;
#pragma unroll
    for (int cc = 0; cc < 4; ++cc) {
        mv[cc] = (cc < nc) ? ml[(size_t)(b * 80 + poff + cc) * 128 + row] : -1e30f;
        M = fmaxf(M, mv[cc]);
    }
    float L = 0.f, accv[16];
#pragma unroll
    for (int j = 0; j < 16; ++j) accv[j] = 0.f;
#pragma unroll
    for (int cc = 0; cc < 4; ++cc) {
        if (cc < nc) {
            const int slot = b * 80 + poff + cc;
            const float w = exp2f(mv[cc] - M);
            L += ml[(size_t)slot * 128 + 64 + row] * w;
            f16x8 o0 = *(const f16x8*)&Opart[(size_t)slot * 4096 + row * 64 + c0];
            f16x8 o1 = *(const f16x8*)&Opart[(size_t)slot * 4096 + row * 64 + c0 + 8];
#pragma unroll
            for (int j = 0; j < 8; ++j) {
                accv[j]     += w * (float)o0[j];
                accv[8 + j] += w * (float)o1[j];
            }
        }
    }
    const float inv = 1.0f / L;
    const size_t obase = ((size_t)b * T_ + qi * 64 + row) * HS_ + c0;
#pragma unroll
    for (int u = 0; u < 4; ++u) {
        float4 r4;
        r4.x = accv[u * 4 + 0] * inv;
        r4.y = accv[u * 4 + 1] * inv;
        r4.z = accv[u * 4 + 2] * inv;
        r4.w = accv[u * 4 + 3] * inv;
        *(float4*)&out[obase + u * 4] = r4;
    }
}

// ---------------------------------------------------------------------------
extern "C" void kernel_launch(void* const* d_in, const int* in_sizes, int n_in,
                              void* d_out, int out_size, void* d_ws, size_t ws_size,
                              hipStream_t stream)
{
    const float* x  = (const float*)d_in[0];
    const float* Wq = (const float*)d_in[1];
    const float* Wk = (const float*)d_in[2];
    const float* Wv = (const float*)d_in[3];
    float* out = (float*)d_out;

    _Float16* w   = (_Float16*)d_ws;
    _Float16* qf  = w;
    _Float16* kf  = w + 1048576;
    _Float16* vT  = w + 2097152;
    _Float16* Wt  = w + 3145728;
    _Float16* Op  = w + 3342336;
    float*    ml  = (float*)(w + 5963776);

    wt_kernel<<<dim3(16, 3), 256, 0, stream>>>(Wq, Wk, Wv, Wt);
    qkv_kernel<<<512, 512, 0, stream>>>(x, Wt, qf, kf, vT);
    attn_kernel<<<dim3(80, 8), 256, 0, stream>>>(qf, kf, vT, Op, ml, out);
    combine_kernel<<<dim3(24, 8), 256, 0, stream>>>(Op, ml, out);
}

// Round 6
// 152.689 us; speedup vs baseline: 1.1410x; 1.1410x over previous
//
#include <hip/hip_runtime.h>
#include <math.h>

#define B_ 8
#define T_ 2048
#define D_ 1024
#define HS_ 64

typedef _Float16 f16x8 __attribute__((ext_vector_type(8)));
typedef float f32x4 __attribute__((ext_vector_type(4)));

typedef __attribute__((address_space(3))) void       lds_void;
typedef const __attribute__((address_space(1))) void gbl_void;
__device__ static inline void async_ld16(gbl_void* g, lds_void* l) {
    // 16 B per lane, HW dest = lds_base + lane*16 (wave-uniform base)
    __builtin_amdgcn_global_load_lds(g, l, 16, 0, 0);
}

// ---------------------------------------------------------------------------
// ws layout (f16 elements unless noted):
//   qf : [B*T][64]      @ 0          (1,048,576)
//   kf : [B*T][64]      @ 1,048,576
//   vT : [B][64][T]     @ 2,097,152
//   Wt : [192][1024]    @ 3,145,728  (196,608)  rows: Wq^T|Wk^T|Wv^T
//   Op : [640][64][64]  @ 3,342,336  (2,621,440) unnormalized O partials
//   ml : [640][128] f32 @ byte 11,927,552 (m[64] then l[64] per slot)
// ---------------------------------------------------------------------------

// Stage 0: transpose Wq|Wk|Wv (fp32 [1024][64]) -> Wt f16 [192][1024]
__global__ __launch_bounds__(256) void wt_kernel(
    const float* __restrict__ Wq, const float* __restrict__ Wk,
    const float* __restrict__ Wv, _Float16* __restrict__ Wt)
{
    __shared__ _Float16 Tt[64][72];
    const float* W = (blockIdx.y == 0) ? Wq : (blockIdx.y == 1) ? Wk : Wv;
    const int t  = threadIdx.x;
    const int k0 = blockIdx.x * 64;
    {
        const int r = t >> 2, c0 = (t & 3) * 16;
#pragma unroll
        for (int i = 0; i < 4; ++i) {
            float4 w = *(const float4*)&W[(size_t)(k0 + r) * HS_ + c0 + i * 4];
            Tt[c0 + i * 4 + 0][r] = (_Float16)w.x;
            Tt[c0 + i * 4 + 1][r] = (_Float16)w.y;
            Tt[c0 + i * 4 + 2][r] = (_Float16)w.z;
            Tt[c0 + i * 4 + 3][r] = (_Float16)w.w;
        }
    }
    __syncthreads();
    {
        const int n = t >> 2, ko = (t & 3) * 16;
        const size_t dst = (size_t)(blockIdx.y * 64 + n) * D_ + k0 + ko;
        *(int4*)&Wt[dst]     = *(int4*)&Tt[n][ko];
        *(int4*)&Wt[dst + 8] = *(int4*)&Tt[n][ko + 8];
    }
}

// ---------------------------------------------------------------------------
// Stage 1: QKV projection, f16 MFMA, m97-style async global->LDS staging.
// Block 256 thr = 4 waves.  M-tile 32, N = 192, BK = 64, grid 512 (2/CU).
// LDS holds fragment-order blocks: every frag read is base+lane*16 (linear
// b128, conflict-free, unpadded as global_load_lds requires).
//   Xs: 8 units  (mt[2] x step[2] x half[2]) of 64 lanes x 16 B  (fp32 x)
//   Ws: 24 units (nt[12] x step[2])          of 64 lanes x 16 B  (f16 Wt)
// Wave w: rows mt=w&1 (16 rows), cols nh=w>>1 (6 n-tiles).  Wave 0 stages
// Xs (8 instrs), waves 1-3 stage Ws (8 instrs each).  2 barriers/chunk.
// ---------------------------------------------------------------------------
__global__ __launch_bounds__(256, 2) void qkv_kernel(
    const float* __restrict__ x, const _Float16* __restrict__ Wt,
    _Float16* __restrict__ qf, _Float16* __restrict__ kf,
    _Float16* __restrict__ vT)
{
    __shared__ float    Xs[8 * 256];    // 8 KB
    __shared__ _Float16 Ws[24 * 512];   // 24 KB
    __shared__ _Float16 CsH[32][200];   // 12.8 KB epilogue pack

    const int t    = threadIdx.x;
    const int m0   = blockIdx.x * 32;
    const int lane = t & 63, wave = t >> 6;
    const int lid  = lane & 15, quad = lane >> 4;
    const int mt   = wave & 1;          // row group (16 rows)
    const int nh   = wave >> 1;         // n-half (6 n-tiles)

    f32x4 acc[6];
#pragma unroll
    for (int i = 0; i < 6; ++i) acc[i] = f32x4{0.f, 0.f, 0.f, 0.f};

    for (int kc = 0; kc < D_; kc += 64) {
        __syncthreads();   // previous chunk's LDS reads complete
        if (wave == 0) {
            // stage x: unit u = mt*4 + st*2 + hf; lane -> 16 B (4 fp32)
#pragma unroll
            for (int u = 0; u < 8; ++u) {
                const int xmt = u >> 2, st = (u >> 1) & 1, hf = u & 1;
                const float* g = x + (size_t)(m0 + xmt * 16 + lid) * D_
                                 + kc + st * 32 + quad * 8 + hf * 4;
                async_ld16((gbl_void*)g, (lds_void*)&Xs[u * 256]);
            }
        } else {
            // stage Wt: unit v = nt*2 + st; lane -> 16 B (8 f16)
#pragma unroll
            for (int i = 0; i < 8; ++i) {
                const int v = (wave - 1) * 8 + i;
                const int nt = v >> 1, st = v & 1;
                const _Float16* g = Wt + (size_t)(nt * 16 + lid) * D_
                                    + kc + st * 32 + quad * 8;
                async_ld16((gbl_void*)g, (lds_void*)&Ws[v * 512]);
            }
        }
        __syncthreads();   // vmcnt(0) drain before barrier => DMA complete

#pragma unroll
        for (int s = 0; s < 2; ++s) {
            const f32x4 alo = *(const f32x4*)&Xs[(mt * 4 + s * 2 + 0) * 256 + lane * 4];
            const f32x4 ahi = *(const f32x4*)&Xs[(mt * 4 + s * 2 + 1) * 256 + lane * 4];
            f16x8 a;
#pragma unroll
            for (int j = 0; j < 4; ++j) {
                a[j]     = (_Float16)alo[j];
                a[4 + j] = (_Float16)ahi[j];
            }
#pragma unroll
            for (int j = 0; j < 6; ++j) {
                const int v = (nh * 6 + j) * 2 + s;
                const f16x8 b = *(const f16x8*)&Ws[v * 512 + lane * 8];
                acc[j] = __builtin_amdgcn_mfma_f32_16x16x32_f16(a, b, acc[j], 0, 0, 0);
            }
        }
    }

    // ---- epilogue: pack f16 in LDS, coalesced writes ----
#pragma unroll
    for (int j = 0; j < 6; ++j)
#pragma unroll
        for (int r = 0; r < 4; ++r)
            CsH[mt * 16 + quad * 4 + r][(nh * 6 + j) * 16 + lid] = (_Float16)acc[j][r];
    __syncthreads();

    {
        const int row = t >> 3;          // 0..31
        const int c8  = (t & 7) * 8;     // 0..56
        const size_t orow = (size_t)(m0 + row) * HS_;
        *(int4*)&qf[orow + c8] = *(int4*)&CsH[row][c8];
        *(int4*)&kf[orow + c8] = *(int4*)&CsH[row][64 + c8];
    }
    {
        const int h  = t >> 2;           // 0..63
        const int mo = (t & 3) * 8;      // 0..24
        _Float16 tmp[8];
#pragma unroll
        for (int j = 0; j < 8; ++j) tmp[j] = CsH[mo + j][128 + h];
        const int bi = m0 >> 11, m0loc = m0 & 2047;
        *(int4*)&vT[(size_t)(bi * 64 + h) * T_ + m0loc + mo] = *(int4*)&tmp[0];
    }
}

// ---------------------------------------------------------------------------
// Stage 2: causal flash attention, split-K (chunks of 8 k-tiles = 512 keys).
// (unchanged from Round 3/4/5)
// ---------------------------------------------------------------------------
__global__ __launch_bounds__(256) void attn_kernel(
    const _Float16* __restrict__ qf, const _Float16* __restrict__ kf,
    const _Float16* __restrict__ vT, _Float16* __restrict__ Opart,
    float* __restrict__ ml, float* __restrict__ out)
{
    __shared__ _Float16 Qs[64][72];
    __shared__ _Float16 Ks[64][72];
    __shared__ _Float16 Vts[64][72];
    __shared__ _Float16 Ps[64][72];

    const int p = blockIdx.x, b = blockIdx.y;
    int qi, c;
    if (p < 8)       { qi = p;                  c = 0; }
    else if (p < 24) { qi = 8  + ((p - 8) >> 1);  c = (p - 8) & 1; }
    else if (p < 48) { qi = 16 + (p - 24) / 3;    c = (p - 24) % 3; }
    else             { qi = 24 + ((p - 48) >> 2); c = (p - 48) & 3; }
    const int kts = c * 8;
    const int kte = min(qi + 1, kts + 8);

    const int q0 = qi * 64;
    const size_t bT = (size_t)b * T_;
    const int t = threadIdx.x;
    const int lane = t & 63, wave = t >> 6;
    const int lid  = lane & 15, quad = lane >> 4;
    const int sr = t >> 2, so = (t & 3) * 16;

    {
        const size_t src = (bT + q0 + sr) * HS_ + so;
        *(int4*)&Qs[sr][so]     = *(const int4*)&qf[src];
        *(int4*)&Qs[sr][so + 8] = *(const int4*)&qf[src + 8];
    }
    __syncthreads();
    const f16x8 aq0 = *(const f16x8*)&Qs[wave * 16 + lid][quad * 8];
    const f16x8 aq1 = *(const f16x8*)&Qs[wave * 16 + lid][32 + quad * 8];

    f32x4 o[4];
#pragma unroll
    for (int i = 0; i < 4; ++i) o[i] = f32x4{0.f, 0.f, 0.f, 0.f};
    float mp[4] = {-1e30f, -1e30f, -1e30f, -1e30f};
    float lr[4] = {0.f, 0.f, 0.f, 0.f};

    const float SC = 0.125f * 1.44269504088896f;   // HS^-0.5 * log2(e)

    int4 kr0, kr1, vr0, vr1;
    {
        const int k0 = kts * 64;
        const size_t ksrc = (bT + k0 + sr) * HS_ + so;
        kr0 = *(const int4*)&kf[ksrc]; kr1 = *(const int4*)&kf[ksrc + 8];
        const size_t vsrc = (size_t)(b * 64 + sr) * T_ + k0 + so;
        vr0 = *(const int4*)&vT[vsrc]; vr1 = *(const int4*)&vT[vsrc + 8];
    }

    for (int kt = kts; kt < kte; ++kt) {
        __syncthreads();
        *(int4*)&Ks[sr][so]      = kr0;
        *(int4*)&Ks[sr][so + 8]  = kr1;
        *(int4*)&Vts[sr][so]     = vr0;
        *(int4*)&Vts[sr][so + 8] = vr1;
        __syncthreads();
        if (kt + 1 < kte) {
            const int k0n = (kt + 1) * 64;
            const size_t ksrc = (bT + k0n + sr) * HS_ + so;
            kr0 = *(const int4*)&kf[ksrc]; kr1 = *(const int4*)&kf[ksrc + 8];
            const size_t vsrc = (size_t)(b * 64 + sr) * T_ + k0n + so;
            vr0 = *(const int4*)&vT[vsrc]; vr1 = *(const int4*)&vT[vsrc + 8];
        }

        f32x4 s[4];
#pragma unroll
        for (int i = 0; i < 4; ++i) s[i] = f32x4{0.f, 0.f, 0.f, 0.f};
#pragma unroll
        for (int nt = 0; nt < 4; ++nt) {
            f16x8 b0 = *(const f16x8*)&Ks[nt * 16 + lid][quad * 8];
            f16x8 b1 = *(const f16x8*)&Ks[nt * 16 + lid][32 + quad * 8];
            s[nt] = __builtin_amdgcn_mfma_f32_16x16x32_f16(aq0, b0, s[nt], 0, 0, 0);
            s[nt] = __builtin_amdgcn_mfma_f32_16x16x32_f16(aq1, b1, s[nt], 0, 0, 0);
        }

        float sv[4][4];
        const bool diag = (kt == qi);
#pragma unroll
        for (int nt = 0; nt < 4; ++nt)
#pragma unroll
            for (int r = 0; r < 4; ++r) {
                float v = s[nt][r] * SC;
                if (diag && (nt * 16 + lid > wave * 16 + quad * 4 + r)) v = -1e30f;
                sv[nt][r] = v;
            }

        float pm[4], al[4], rs[4];
#pragma unroll
        for (int r = 0; r < 4; ++r)
            pm[r] = fmaxf(fmaxf(sv[0][r], sv[1][r]), fmaxf(sv[2][r], sv[3][r]));
#pragma unroll
        for (int d = 1; d < 16; d <<= 1)
#pragma unroll
            for (int r = 0; r < 4; ++r)
                pm[r] = fmaxf(pm[r], __shfl_xor(pm[r], d, 64));
#pragma unroll
        for (int r = 0; r < 4; ++r) {
            const float mn = fmaxf(mp[r], pm[r]);
            al[r] = exp2f(mp[r] - mn);
            mp[r] = mn;
            rs[r] = 0.f;
        }
#pragma unroll
        for (int nt = 0; nt < 4; ++nt)
#pragma unroll
            for (int r = 0; r < 4; ++r) {
                const float pv = exp2f(sv[nt][r] - mp[r]);
                sv[nt][r] = pv;
                rs[r] += pv;
            }
#pragma unroll
        for (int d = 1; d < 16; d <<= 1)
#pragma unroll
            for (int r = 0; r < 4; ++r)
                rs[r] += __shfl_xor(rs[r], d, 64);
#pragma unroll
        for (int r = 0; r < 4; ++r)
            lr[r] = lr[r] * al[r] + rs[r];
#pragma unroll
        for (int nt = 0; nt < 4; ++nt)
#pragma unroll
            for (int r = 0; r < 4; ++r)
                o[nt][r] *= al[r];

#pragma unroll
        for (int nt = 0; nt < 4; ++nt)
#pragma unroll
            for (int r = 0; r < 4; ++r)
                Ps[wave * 16 + quad * 4 + r][nt * 16 + lid] = (_Float16)sv[nt][r];

        const f16x8 ap0 = *(const f16x8*)&Ps[wave * 16 + lid][quad * 8];
        const f16x8 ap1 = *(const f16x8*)&Ps[wave * 16 + lid][32 + quad * 8];
#pragma unroll
        for (int nt = 0; nt < 4; ++nt) {
            f16x8 b0 = *(const f16x8*)&Vts[nt * 16 + lid][quad * 8];
            f16x8 b1 = *(const f16x8*)&Vts[nt * 16 + lid][32 + quad * 8];
            o[nt] = __builtin_amdgcn_mfma_f32_16x16x32_f16(ap0, b0, o[nt], 0, 0, 0);
            o[nt] = __builtin_amdgcn_mfma_f32_16x16x32_f16(ap1, b1, o[nt], 0, 0, 0);
        }
    }

    const int nc = (qi >> 3) + 1;
    if (nc == 1) {
        float inv[4];
#pragma unroll
        for (int r = 0; r < 4; ++r) inv[r] = 1.0f / lr[r];
#pragma unroll
        for (int nt = 0; nt < 4; ++nt)
#pragma unroll
            for (int r = 0; r < 4; ++r)
                out[(bT + q0 + wave * 16 + quad * 4 + r) * HS_ + nt * 16 + lid] =
                    o[nt][r] * inv[r];
    } else {
        const int slot = b * 80 + p;
        _Float16* Ob = Opart + (size_t)slot * 4096;
#pragma unroll
        for (int nt = 0; nt < 4; ++nt)
#pragma unroll
            for (int r = 0; r < 4; ++r)
                Ob[(wave * 16 + quad * 4 + r) * 64 + nt * 16 + lid] = (_Float16)o[nt][r];
        if (lid == 0) {
#pragma unroll
            for (int r = 0; r < 4; ++r) {
                const int row = wave * 16 + quad * 4 + r;
                ml[(size_t)slot * 128 + row]      = mp[r];
                ml[(size_t)slot * 128 + 64 + row] = lr[r];
            }
        }
    }
}

// ---------------------------------------------------------------------------
// Stage 3: combine partials for q-tiles with >=2 chunks (qi >= 8).
// (unchanged)
// ---------------------------------------------------------------------------
__global__ __launch_bounds__(256) void combine_kernel(
    const _Float16* __restrict__ Opart, const float* __restrict__ ml,
    float* __restrict__ out)
{
    const int qi = 8 + blockIdx.x, b = blockIdx.y;
    const int g = qi >> 3, nc = g + 1;
    const int poff = 8 * (g * (g + 1) / 2) + (qi & 7) * nc;
    const int t = threadIdx.x, row = t >> 2, c0 = (t & 3) * 16;

    float mv[4], M = -1e30f;
#pragma unroll
    for (int cc = 0; cc < 4; ++cc) {
        mv[cc] = (cc < nc) ? ml[(size_t)(b * 80 + poff + cc) * 128 + row] : -1e30f;
        M = fmaxf(M, mv[cc]);
    }
    float L = 0.f, accv[16];
#pragma unroll
    for (int j = 0; j < 16; ++j) accv[j] = 0.f;
#pragma unroll
    for (int cc = 0; cc < 4; ++cc) {
        if (cc < nc) {
            const int slot = b * 80 + poff + cc;
            const float w = exp2f(mv[cc] - M);
            L += ml[(size_t)slot * 128 + 64 + row] * w;
            f16x8 o0 = *(const f16x8*)&Opart[(size_t)slot * 4096 + row * 64 + c0];
            f16x8 o1 = *(const f16x8*)&Opart[(size_t)slot * 4096 + row * 64 + c0 + 8];
#pragma unroll
            for (int j = 0; j < 8; ++j) {
                accv[j]     += w * (float)o0[j];
                accv[8 + j] += w * (float)o1[j];
            }
        }
    }
    const float inv = 1.0f / L;
    const size_t obase = ((size_t)b * T_ + qi * 64 + row) * HS_ + c0;
#pragma unroll
    for (int u = 0; u < 4; ++u) {
        float4 r4;
        r4.x = accv[u * 4 + 0] * inv;
        r4.y = accv[u * 4 + 1] * inv;
        r4.z = accv[u * 4 + 2] * inv;
        r4.w = accv[u * 4 + 3] * inv;
        *(float4*)&out[obase + u * 4] = r4;
    }
}

// ---------------------------------------------------------------------------
extern "C" void kernel_launch(void* const* d_in, const int* in_sizes, int n_in,
                              void* d_out, int out_size, void* d_ws, size_t ws_size,
                              hipStream_t stream)
{
    const float* x  = (const float*)d_in[0];
    const float* Wq = (const float*)d_in[1];
    const float* Wk = (const float*)d_in[2];
    const float* Wv = (const float*)d_in[3];
    float* out = (float*)d_out;

    _Float16* w   = (_Float16*)d_ws;
    _Float16* qf  = w;
    _Float16* kf  = w + 1048576;
    _Float16* vT  = w + 2097152;
    _Float16* Wt  = w + 3145728;
    _Float16* Op  = w + 3342336;
    float*    ml  = (float*)(w + 5963776);

    wt_kernel<<<dim3(16, 3), 256, 0, stream>>>(Wq, Wk, Wv, Wt);
    qkv_kernel<<<512, 256, 0, stream>>>(x, Wt, qf, kf, vT);
    attn_kernel<<<dim3(80, 8), 256, 0, stream>>>(qf, kf, vT, Op, ml, out);
    combine_kernel<<<dim3(24, 8), 256, 0, stream>>>(Op, ml, out);
}

// Round 7
// 137.947 us; speedup vs baseline: 1.2629x; 1.1069x over previous
//
#include <hip/hip_runtime.h>
#include <math.h>

#define B_ 8
#define T_ 2048
#define D_ 1024
#define HS_ 64

typedef _Float16 f16x8 __attribute__((ext_vector_type(8)));
typedef float f32x4 __attribute__((ext_vector_type(4)));

typedef __attribute__((address_space(3))) void       lds_void;
typedef const __attribute__((address_space(1))) void gbl_void;
__device__ static inline void async_ld16(gbl_void* g, lds_void* l) {
    // 16 B per lane, HW dest = lds_base + lane*16 (wave-uniform base)
    __builtin_amdgcn_global_load_lds(g, l, 16, 0, 0);
}

// ---------------------------------------------------------------------------
// ws layout (f16 elements unless noted):
//   qf    : [B*T][64]        @ 0          (1,048,576)
//   kf    : [B*T][64]        @ 1,048,576
//   vT    : [B][64][T]       @ 2,097,152
//   Wfrag : fragment-packed  @ 3,145,728  (196,608)
//           unit u = (c*12 + nt)*4 + s  (c: k-chunk of 128, nt: n-tile, s: k-step 32)
//           elem: Wfrag[u*512 + lane*8 + e] = W[n=nt*16+(lane&15)][k=c*128+s*32+(lane>>4)*8+e]
//   Op    : [1152][64][64]   @ 3,342,336  (4,718,592) unnormalized O partials
//   ml    : [1152][128] f32  @ f16-idx 8,060,928  (m[64] then l[64] per slot)
// ---------------------------------------------------------------------------

// Stage 0: Wq|Wk|Wv (fp32 [1024][64]) -> Wfrag (f16, MFMA-fragment order)
__global__ __launch_bounds__(256) void wt_kernel(
    const float* __restrict__ Wq, const float* __restrict__ Wk,
    const float* __restrict__ Wv, _Float16* __restrict__ Wfrag)
{
    __shared__ _Float16 Tt[64][72];   // Tt[h][k_local]
    const int my = blockIdx.y;        // matrix 0,1,2
    const float* W = (my == 0) ? Wq : (my == 1) ? Wk : Wv;
    const int t  = threadIdx.x;
    const int kb = blockIdx.x;        // 64-k block
    const int k0 = kb * 64;
    {
        const int r = t >> 2, c0 = (t & 3) * 16;   // r = k row, c0 = h base
#pragma unroll
        for (int i = 0; i < 4; ++i) {
            float4 w = *(const float4*)&W[(size_t)(k0 + r) * HS_ + c0 + i * 4];
            Tt[c0 + i * 4 + 0][r] = (_Float16)w.x;
            Tt[c0 + i * 4 + 1][r] = (_Float16)w.y;
            Tt[c0 + i * 4 + 2][r] = (_Float16)w.z;
            Tt[c0 + i * 4 + 3][r] = (_Float16)w.w;
        }
    }
    __syncthreads();
    {
        const int lane = t & 63, j = t >> 6;       // j = n-tile within matrix
        const int lid = lane & 15, quad = lane >> 4;
        const int c = kb >> 1, shalf = kb & 1;
        const int nt = my * 4 + j;
#pragma unroll
        for (int s2 = 0; s2 < 2; ++s2) {
            const int u = (c * 12 + nt) * 4 + shalf * 2 + s2;
            *(int4*)&Wfrag[(size_t)u * 512 + lane * 8] =
                *(int4*)&Tt[j * 16 + lid][s2 * 32 + quad * 8];
        }
    }
}

// ---------------------------------------------------------------------------
// Stage 1: QKV projection, f16 MFMA, async staging with CONTIGUOUS global
// reads.  Block 256 thr = 4 waves; M-tile 32, N = 192, BK = 128 (8 chunks).
//   Xs: 16 units (2 rows x 512 B) stride 1040 B (pad kills bank aliasing)
//   Ws: 48 units (1 KB frag-order, linear) -- global side contiguous 1 KB
// Wave w: rows mt=w&1 (16), cols nh=w>>1 (6 n-tiles).  2 barriers/chunk.
// ---------------------------------------------------------------------------
__global__ __launch_bounds__(256, 2) void qkv_kernel(
    const float* __restrict__ x, const _Float16* __restrict__ Wfrag,
    _Float16* __restrict__ qf, _Float16* __restrict__ kf,
    _Float16* __restrict__ vT)
{
    __shared__ __align__(16) char smem[65792];        // Xs 16640 | Ws 49152
    _Float16* Ws = (_Float16*)(smem + 16640);
    _Float16 (*CsH)[200] = (_Float16(*)[200])smem;     // epilogue overlay

    const int t    = threadIdx.x;
    const int m0   = blockIdx.x * 32;
    const int lane = t & 63, wave = t >> 6;
    const int lid  = lane & 15, quad = lane >> 4;
    const int mt   = wave & 1;          // row group (16 rows)
    const int nh   = wave >> 1;         // n-half (6 n-tiles)

    f32x4 acc[6];
#pragma unroll
    for (int i = 0; i < 6; ++i) acc[i] = f32x4{0.f, 0.f, 0.f, 0.f};

    for (int c = 0; c < 8; ++c) {
        const int kc = c * 128;
        __syncthreads();   // previous chunk's LDS reads complete
        // x: 4 units/wave, each 2 rows x 512 B contiguous segments
#pragma unroll
        for (int i = 0; i < 4; ++i) {
            const int xu = wave * 4 + i;
            const float* g = x + (size_t)(m0 + xu * 2 + (lane >> 5)) * D_
                             + kc + (lane & 31) * 4;
            async_ld16((gbl_void*)g, (lds_void*)(smem + xu * 1040));
        }
        // Wfrag: 12 units/wave, each 1 KB fully contiguous
#pragma unroll
        for (int i = 0; i < 12; ++i) {
            const int v = wave * 12 + i;
            const _Float16* g = Wfrag + (size_t)(c * 48 + v) * 512 + lane * 8;
            async_ld16((gbl_void*)g, (lds_void*)&Ws[v * 512]);
        }
        __syncthreads();   // vmcnt(0) drain => DMA complete

#pragma unroll
        for (int s = 0; s < 4; ++s) {
            const int row = mt * 16 + lid;
            const int xoff = (row >> 1) * 1040 + (row & 1) * 512
                             + (s * 32 + quad * 8) * 4;
            const f32x4 alo = *(const f32x4*)(smem + xoff);
            const f32x4 ahi = *(const f32x4*)(smem + xoff + 16);
            f16x8 a;
#pragma unroll
            for (int j = 0; j < 4; ++j) {
                a[j]     = (_Float16)alo[j];
                a[4 + j] = (_Float16)ahi[j];
            }
#pragma unroll
            for (int j = 0; j < 6; ++j) {
                const int v = (nh * 6 + j) * 4 + s;
                const f16x8 b = *(const f16x8*)&Ws[v * 512 + lane * 8];
                acc[j] = __builtin_amdgcn_mfma_f32_16x16x32_f16(a, b, acc[j], 0, 0, 0);
            }
        }
    }
    __syncthreads();   // all staging reads done before overlay writes

    // ---- epilogue: pack f16 in LDS, coalesced writes ----
#pragma unroll
    for (int j = 0; j < 6; ++j)
#pragma unroll
        for (int r = 0; r < 4; ++r)
            CsH[mt * 16 + quad * 4 + r][(nh * 6 + j) * 16 + lid] = (_Float16)acc[j][r];
    __syncthreads();

    {
        const int row = t >> 3;          // 0..31
        const int c8  = (t & 7) * 8;     // 0..56
        const size_t orow = (size_t)(m0 + row) * HS_;
        *(int4*)&qf[orow + c8] = *(int4*)&CsH[row][c8];
        *(int4*)&kf[orow + c8] = *(int4*)&CsH[row][64 + c8];
    }
    {
        const int h  = t >> 2;           // 0..63
        const int mo = (t & 3) * 8;      // 0..24
        _Float16 tmp[8];
#pragma unroll
        for (int j = 0; j < 8; ++j) tmp[j] = CsH[mo + j][128 + h];
        const int bi = m0 >> 11, m0loc = m0 & 2047;
        *(int4*)&vT[(size_t)(bi * 64 + h) * T_ + m0loc + mo] = *(int4*)&tmp[0];
    }
}

// ---------------------------------------------------------------------------
// Stage 2: causal flash attention, split-K chunks of 4 k-tiles (256 keys).
// Grid (144, 8): group g = qi>>2 has 4 q-tiles x (g+1) chunks, offset 2g(g+1).
// 4.5 blocks/CU co-resident; max 4 iterations per block.
// ---------------------------------------------------------------------------
__global__ __launch_bounds__(256, 4) void attn_kernel(
    const _Float16* __restrict__ qf, const _Float16* __restrict__ kf,
    const _Float16* __restrict__ vT, _Float16* __restrict__ Opart,
    float* __restrict__ ml, float* __restrict__ out)
{
    __shared__ _Float16 Qs[64][72];
    __shared__ _Float16 Ks[64][72];
    __shared__ _Float16 Vts[64][72];
    __shared__ _Float16 Ps[64][72];

    const int p = blockIdx.x, b = blockIdx.y;
    int g = 0;
    while (p >= 2 * (g + 1) * (g + 2)) ++g;
    const int rem = p - 2 * g * (g + 1);
    const int qi  = 4 * g + rem / (g + 1);
    const int c   = rem % (g + 1);
    const int kts = c * 4;
    const int kte = min(qi + 1, kts + 4);

    const int q0 = qi * 64;
    const size_t bT = (size_t)b * T_;
    const int t = threadIdx.x;
    const int lane = t & 63, wave = t >> 6;
    const int lid  = lane & 15, quad = lane >> 4;
    const int sr = t >> 2, so = (t & 3) * 16;

    {
        const size_t src = (bT + q0 + sr) * HS_ + so;
        *(int4*)&Qs[sr][so]     = *(const int4*)&qf[src];
        *(int4*)&Qs[sr][so + 8] = *(const int4*)&qf[src + 8];
    }
    __syncthreads();
    const f16x8 aq0 = *(const f16x8*)&Qs[wave * 16 + lid][quad * 8];
    const f16x8 aq1 = *(const f16x8*)&Qs[wave * 16 + lid][32 + quad * 8];

    f32x4 o[4];
#pragma unroll
    for (int i = 0; i < 4; ++i) o[i] = f32x4{0.f, 0.f, 0.f, 0.f};
    float mp[4] = {-1e30f, -1e30f, -1e30f, -1e30f};
    float lr[4] = {0.f, 0.f, 0.f, 0.f};

    const float SC = 0.125f * 1.44269504088896f;   // HS^-0.5 * log2(e)

    int4 kr0, kr1, vr0, vr1;
    {
        const int k0 = kts * 64;
        const size_t ksrc = (bT + k0 + sr) * HS_ + so;
        kr0 = *(const int4*)&kf[ksrc]; kr1 = *(const int4*)&kf[ksrc + 8];
        const size_t vsrc = (size_t)(b * 64 + sr) * T_ + k0 + so;
        vr0 = *(const int4*)&vT[vsrc]; vr1 = *(const int4*)&vT[vsrc + 8];
    }

    for (int kt = kts; kt < kte; ++kt) {
        __syncthreads();
        *(int4*)&Ks[sr][so]      = kr0;
        *(int4*)&Ks[sr][so + 8]  = kr1;
        *(int4*)&Vts[sr][so]     = vr0;
        *(int4*)&Vts[sr][so + 8] = vr1;
        __syncthreads();
        if (kt + 1 < kte) {
            const int k0n = (kt + 1) * 64;
            const size_t ksrc = (bT + k0n + sr) * HS_ + so;
            kr0 = *(const int4*)&kf[ksrc]; kr1 = *(const int4*)&kf[ksrc + 8];
            const size_t vsrc = (size_t)(b * 64 + sr) * T_ + k0n + so;
            vr0 = *(const int4*)&vT[vsrc]; vr1 = *(const int4*)&vT[vsrc + 8];
        }

        f32x4 s[4];
#pragma unroll
        for (int i = 0; i < 4; ++i) s[i] = f32x4{0.f, 0.f, 0.f, 0.f};
#pragma unroll
        for (int nt = 0; nt < 4; ++nt) {
            f16x8 b0 = *(const f16x8*)&Ks[nt * 16 + lid][quad * 8];
            f16x8 b1 = *(const f16x8*)&Ks[nt * 16 + lid][32 + quad * 8];
            s[nt] = __builtin_amdgcn_mfma_f32_16x16x32_f16(aq0, b0, s[nt], 0, 0, 0);
            s[nt] = __builtin_amdgcn_mfma_f32_16x16x32_f16(aq1, b1, s[nt], 0, 0, 0);
        }

        float sv[4][4];
        const bool diag = (kt == qi);
#pragma unroll
        for (int nt = 0; nt < 4; ++nt)
#pragma unroll
            for (int r = 0; r < 4; ++r) {
                float v = s[nt][r] * SC;
                if (diag && (nt * 16 + lid > wave * 16 + quad * 4 + r)) v = -1e30f;
                sv[nt][r] = v;
            }

        float pm[4], al[4], rs[4];
#pragma unroll
        for (int r = 0; r < 4; ++r)
            pm[r] = fmaxf(fmaxf(sv[0][r], sv[1][r]), fmaxf(sv[2][r], sv[3][r]));
#pragma unroll
        for (int d = 1; d < 16; d <<= 1)
#pragma unroll
            for (int r = 0; r < 4; ++r)
                pm[r] = fmaxf(pm[r], __shfl_xor(pm[r], d, 64));
#pragma unroll
        for (int r = 0; r < 4; ++r) {
            const float mn = fmaxf(mp[r], pm[r]);
            al[r] = exp2f(mp[r] - mn);
            mp[r] = mn;
            rs[r] = 0.f;
        }
#pragma unroll
        for (int nt = 0; nt < 4; ++nt)
#pragma unroll
            for (int r = 0; r < 4; ++r) {
                const float pv = exp2f(sv[nt][r] - mp[r]);
                sv[nt][r] = pv;
                rs[r] += pv;
            }
#pragma unroll
        for (int d = 1; d < 16; d <<= 1)
#pragma unroll
            for (int r = 0; r < 4; ++r)
                rs[r] += __shfl_xor(rs[r], d, 64);
#pragma unroll
        for (int r = 0; r < 4; ++r)
            lr[r] = lr[r] * al[r] + rs[r];
#pragma unroll
        for (int nt = 0; nt < 4; ++nt)
#pragma unroll
            for (int r = 0; r < 4; ++r)
                o[nt][r] *= al[r];

#pragma unroll
        for (int nt = 0; nt < 4; ++nt)
#pragma unroll
            for (int r = 0; r < 4; ++r)
                Ps[wave * 16 + quad * 4 + r][nt * 16 + lid] = (_Float16)sv[nt][r];

        const f16x8 ap0 = *(const f16x8*)&Ps[wave * 16 + lid][quad * 8];
        const f16x8 ap1 = *(const f16x8*)&Ps[wave * 16 + lid][32 + quad * 8];
#pragma unroll
        for (int nt = 0; nt < 4; ++nt) {
            f16x8 b0 = *(const f16x8*)&Vts[nt * 16 + lid][quad * 8];
            f16x8 b1 = *(const f16x8*)&Vts[nt * 16 + lid][32 + quad * 8];
            o[nt] = __builtin_amdgcn_mfma_f32_16x16x32_f16(ap0, b0, o[nt], 0, 0, 0);
            o[nt] = __builtin_amdgcn_mfma_f32_16x16x32_f16(ap1, b1, o[nt], 0, 0, 0);
        }
    }

    if (g == 0) {   // single chunk: write final output
        float inv[4];
#pragma unroll
        for (int r = 0; r < 4; ++r) inv[r] = 1.0f / lr[r];
#pragma unroll
        for (int nt = 0; nt < 4; ++nt)
#pragma unroll
            for (int r = 0; r < 4; ++r)
                out[(bT + q0 + wave * 16 + quad * 4 + r) * HS_ + nt * 16 + lid] =
                    o[nt][r] * inv[r];
    } else {
        const int slot = b * 144 + p;
        _Float16* Ob = Opart + (size_t)slot * 4096;
#pragma unroll
        for (int nt = 0; nt < 4; ++nt)
#pragma unroll
            for (int r = 0; r < 4; ++r)
                Ob[(wave * 16 + quad * 4 + r) * 64 + nt * 16 + lid] = (_Float16)o[nt][r];
        if (lid == 0) {
#pragma unroll
            for (int r = 0; r < 4; ++r) {
                const int row = wave * 16 + quad * 4 + r;
                ml[(size_t)slot * 128 + row]      = mp[r];
                ml[(size_t)slot * 128 + 64 + row] = lr[r];
            }
        }
    }
}

// ---------------------------------------------------------------------------
// Stage 3: combine partials for q-tiles with >=2 chunks (qi >= 4).
// ---------------------------------------------------------------------------
__global__ __launch_bounds__(256) void combine_kernel(
    const _Float16* __restrict__ Opart, const float* __restrict__ ml,
    float* __restrict__ out)
{
    const int qi = 4 + blockIdx.x, b = blockIdx.y;
    const int g = qi >> 2, nc = g + 1;
    const int poff = 2 * g * (g + 1) + (qi & 3) * (g + 1);
    const int t = threadIdx.x, row = t >> 2, c0 = (t & 3) * 16;

    float mv[8], M = -1e30f;
#pragma unroll
    for (int cc = 0; cc < 8; ++cc) {
        mv[cc] = (cc < nc) ? ml[(size_t)(b * 144 + poff + cc) * 128 + row] : -1e30f;
        M = fmaxf(M, mv[cc]);
    }
    float L = 0.f, accv[16];
#pragma unroll
    for (int j = 0; j < 16; ++j) accv[j] = 0.f;
#pragma unroll
    for (int cc = 0; cc < 8; ++cc) {
        if (cc < nc) {   // nc is block-uniform: no divergence
            const int slot = b * 144 + poff + cc;
            const float w = exp2f(mv[cc] - M);
            L += ml[(size_t)slot * 128 + 64 + row] * w;
            f16x8 o0 = *(const f16x8*)&Opart[(size_t)slot * 4096 + row * 64 + c0];
            f16x8 o1 = *(const f16x8*)&Opart[(size_t)slot * 4096 + row * 64 + c0 + 8];
#pragma unroll
            for (int j = 0; j < 8; ++j) {
                accv[j]     += w * (float)o0[j];
                accv[8 + j] += w * (float)o1[j];
            }
        }
    }
    const float inv = 1.0f / L;
    const size_t obase = ((size_t)b * T_ + qi * 64 + row) * HS_ + c0;
#pragma unroll
    for (int u = 0; u < 4; ++u) {
        float4 r4;
        r4.x = accv[u * 4 + 0] * inv;
        r4.y = accv[u * 4 + 1] * inv;
        r4.z = accv[u * 4 + 2] * inv;
        r4.w = accv[u * 4 + 3] * inv;
        *(float4*)&out[obase + u * 4] = r4;
    }
}

// ---------------------------------------------------------------------------
extern "C" void kernel_launch(void* const* d_in, const int* in_sizes, int n_in,
                              void* d_out, int out_size, void* d_ws, size_t ws_size,
                              hipStream_t stream)
{
    const float* x  = (const float*)d_in[0];
    const float* Wq = (const float*)d_in[1];
    const float* Wk = (const float*)d_in[2];
    const float* Wv = (const float*)d_in[3];
    float* out = (float*)d_out;

    _Float16* w    = (_Float16*)d_ws;
    _Float16* qf    = w;
    _Float16* kf    = w + 1048576;
    _Float16* vT    = w + 2097152;
    _Float16* Wfrag = w + 3145728;
    _Float16* Op    = w + 3342336;            // + 196,608
    float*    ml    = (float*)(w + 8060928);  // Op + 4,718,592

    wt_kernel<<<dim3(16, 3), 256, 0, stream>>>(Wq, Wk, Wv, Wfrag);
    qkv_kernel<<<512, 256, 0, stream>>>(x, Wfrag, qf, kf, vT);
    attn_kernel<<<dim3(144, 8), 256, 0, stream>>>(qf, kf, vT, Op, ml, out);
    combine_kernel<<<dim3(28, 8), 256, 0, stream>>>(Op, ml, out);
}